// Round 5
// baseline (554.393 us; speedup 1.0000x reference)
//
#include <hip/hip_runtime.h>

#define TOK  10560
#define CIMG 3072
#define KHD  1024

typedef unsigned short ushort_t;
typedef unsigned int u32;
using bf16x8 = __attribute__((ext_vector_type(8))) __bf16;
using f32x4  = __attribute__((ext_vector_type(4))) float;

#define GLD_LDS16(gp, lp) __builtin_amdgcn_global_load_lds( \
    (const __attribute__((address_space(1))) u32*)(gp), \
    (__attribute__((address_space(3))) u32*)(lp), 16, 0, 0)

static __device__ __forceinline__ unsigned short f2bf(float f){
  union { float f; unsigned u; } x; x.f = f;
  unsigned r = x.u + 0x7fffu + ((x.u >> 16) & 1u);
  return (unsigned short)(r >> 16);
}
static __device__ __forceinline__ float bf2f(unsigned short u){
  union { unsigned u; float f; } x; x.u = ((unsigned)u) << 16; return x.f;
}
static __device__ __forceinline__ float wave_sum(float v){
  #pragma unroll
  for (int off = 32; off > 0; off >>= 1) v += __shfl_xor(v, off, 64);
  return v;
}

// ---------------- conditioning MLP: emb rows 72..87 (cond rows 64..79) -------
__global__ void k_pre(const float* __restrict__ cond,
                      const float* __restrict__ w1, const float* __restrict__ b1,
                      const float* __restrict__ w2, const float* __restrict__ b2,
                      float* __restrict__ emb){
  __shared__ float cs[16][16];
  __shared__ float h1[16][512];
  int t = threadIdx.x;
  if (t < 256) cs[t >> 4][t & 15] = cond[(64 + (t >> 4)) * 16 + (t & 15)];
  __syncthreads();
  #pragma unroll
  for (int i = 0; i < 8; ++i){
    int idx = t + i * 1024; int r = idx >> 9, c = idx & 511;
    float s = b1[c];
    #pragma unroll
    for (int j = 0; j < 16; ++j) s += cs[r][j] * w1[j * 512 + c];
    h1[r][c] = s / (1.f + __expf(-s));   // silu
  }
  __syncthreads();
  #pragma unroll
  for (int i = 0; i < 8; ++i){
    int idx = t + i * 1024; int r = idx >> 9, c = idx & 511;
    float e = b2[c];
    for (int j = 0; j < 512; ++j) e += h1[r][j] * w2[j * 512 + c];
    emb[idx] = e;
  }
}

// ---------------- kv = mf @ kv_w, split-K partials (deterministic) ----------
__global__ __launch_bounds__(256) void k_kv(const float* __restrict__ emb,
                                            const float* __restrict__ kvw,
                                            float* __restrict__ part){
  int bl = blockIdx.x;                 // 3 l * 8 ntile * 16 kchunk = 384
  int l = bl / 128, rem = bl % 128, nt = rem / 16, kc = rem % 16;
  int n = nt * 256 + threadIdx.x;
  const float* e = emb + 2048 * l + kc * 256;   // mf[l][r] = emb[2048l + r]
  const float* w = kvw + (size_t)(kc * 256) * 2048 + n;
  float acc = 0.f;
  for (int r = 0; r < 256; ++r) acc += e[r] * w[(size_t)r * 2048];
  part[kc * 6144 + l * 2048 + n] = acc;
}

// ---------------- reduce partials, bias, k-RMSNorm ---------------------------
__global__ void k_knorm(const float* __restrict__ part, const float* __restrict__ kvb,
                        const float* __restrict__ knw, float* __restrict__ kn,
                        float* __restrict__ vv){
  int wid = threadIdx.x >> 6, lane = threadIdx.x & 63;
  for (int i = 0; i < 12; ++i){
    int g = wid * 12 + i;               // 0..47 = (l,h)
    int l = g >> 4, h = g & 15;
    int ik = l * 2048 + h * 64 + lane;
    float kk = kvb[h * 64 + lane];
    float v  = kvb[1024 + h * 64 + lane];
    for (int p = 0; p < 16; ++p){ kk += part[p * 6144 + ik]; v += part[p * 6144 + ik + 1024]; }
    float ss = wave_sum(kk * kk);
    kn[l * 1024 + h * 64 + lane] = kk * rsqrtf(ss * (1.f/64.f) + 1e-6f) * knw[lane];
    vv[l * 1024 + h * 64 + lane] = v;
  }
}

// ---------------- transpose + f32->bf16 weight convert: dst[C][R] ------------
__global__ __launch_bounds__(256) void k_tconv(const float* __restrict__ src,
                                               ushort_t* __restrict__ dst,
                                               int R, int C){
  __shared__ float tile[32][33];
  int nTr = R >> 5;
  int tr = blockIdx.x % nTr, tc = blockIdx.x / nTr;
  int r0 = tr * 32, c0 = tc * 32, t = threadIdx.x;
  #pragma unroll
  for (int i = 0; i < 4; ++i){
    int idx = t + i * 256; int r = idx >> 5, c = idx & 31;
    tile[r][c] = src[(size_t)(r0 + r) * C + c0 + c];
  }
  __syncthreads();
  #pragma unroll
  for (int i = 0; i < 4; ++i){
    int idx = t + i * 256; int rr = idx >> 5, cc = idx & 31;
    dst[(size_t)(c0 + rr) * R + r0 + cc] = f2bf(tile[cc][rr]);
  }
}

// ---------------- x f32 -> bf16 streaming convert ----------------------------
__global__ __launch_bounds__(256) void k_xconv(const float* __restrict__ x,
                                               ushort_t* __restrict__ xb, int n4){
  for (int i = blockIdx.x * 256 + threadIdx.x; i < n4; i += gridDim.x * 256){
    float4 v = ((const float4*)x)[i];
    ushort4 o;
    o.x = f2bf(v.x); o.y = f2bf(v.y); o.z = f2bf(v.z); o.w = f2bf(v.w);
    ((ushort4*)xb)[i] = o;
  }
}

// ============ 256x256 bf16 MFMA GEMM, m201-style 8-phase schedule ============
// A bf16 [M][K], Bt bf16 [N][K]. K-tile BK=64, split into 4 k-chunks of 16.
// LDS: 2 buffers x 64KB; buffer = A[4 chunks][256 rows][32B] + B same @+32KB.
// Swizzle: within a row's 32B, k-half slot s holds global k-half s^((row>>2)&1)
//   (applied to gload source; reads XOR the same bit) -> 2-way banks = free.
// Phase p of tile t: {ds_read frags, stage chunk p of tile t+1, [vmcnt(4) at
//   odd p], barrier, 16 MFMA (setprio), barrier}.
// vmcnt ledger (2 loads per thread per chunk-stage, in-order completion):
//   entering tile t: chunks 2,3 of t outstanding (4 loads).
//   phase1 wait: outstanding {c2,c3(t), c0,c1(t+1)}=8 -> vmcnt(4) waits c2,c3(t)
//   phase3 wait: outstanding {c0..c3(t+1)}=8 -> vmcnt(4) waits c0,c1(t+1).
// Last tile peeled: no staging, phase1 drains vmcnt(0).
// EPI 0: out bf16 = acc + bias (LDS-coalesced).  EPI 1: out f32 = acc+bias+resid.
template<int EPI>
__global__ __launch_bounds__(512, 2) void gemm8p(
    const ushort_t* __restrict__ A, const ushort_t* __restrict__ Bt,
    int Mdim, int Kdim, int Ndim,
    const float* __restrict__ bias, const float* __restrict__ resid,
    void* __restrict__ outp){
  __shared__ __align__(16) unsigned char lds[131072];
  const int tid = threadIdx.x;
  const int lane = tid & 63, wid = tid >> 6;
  const int wm = wid >> 2, wn = wid & 3;     // 2 x 4 waves -> per-wave 128x64
  const int l15 = lane & 15, kg = lane >> 4;
  const int ntiles = Ndim >> 8;

  // XCD swizzle (grids 168 / 504 both divisible by 8 -> bijective)
  int bid = blockIdx.x;
  const int cpx = gridDim.x >> 3;
  bid = (bid & 7) * cpx + (bid >> 3);
  const int mt = bid / ntiles, nt = bid % ntiles;
  const int mbase = mt << 8, nbase = nt << 8;

  // ---- staging: thread -> (row sr, swizzled k-half skh); 2 gloads per chunk
  const int sr  = tid >> 1;                       // 0..255
  const int skh = (tid & 1) ^ ((sr >> 2) & 1);    // inverse swizzle on source
  int arow = mbase + sr; if (arow >= Mdim) arow = Mdim - 1;
  const ushort_t* gA = A  + (size_t)arow * Kdim + skh * 8;
  const ushort_t* gB = Bt + (size_t)(nbase + sr) * Kdim + skh * 8;
  const int wofs = wid * 1024;                    // wave-uniform LDS base part

  auto stage = [&](int t, int c, int b){
    const int gk = t * 64 + c * 16;
    unsigned char* dst = lds + b * 65536 + c * 8192 + wofs;
    GLD_LDS16(gA + gk, dst);            // lanes auto-offset +lane*16
    GLD_LDS16(gB + gk, dst + 32768);
  };

  // ---- fragment read bases (byte offsets inside a buffer)
  const int arl = wm * 128 + l15;
  const int brl = wn * 64 + l15;
  const int kh  = ((kg & 1) ^ ((l15 >> 2) & 1)) * 16;   // read-side swizzle
  const unsigned aBase = (unsigned)((kg >> 1) * 8192 + arl * 32 + kh);
  const unsigned bBase = (unsigned)(32768 + (kg >> 1) * 8192 + brl * 32 + kh);
  // frag(m,ksl) at aBase + ksl*16384 + m*512 ; frag(n,ksl) at bBase + ...

  f32x4 acc[8][4];
  #pragma unroll
  for (int m = 0; m < 8; ++m)
    #pragma unroll
    for (int n = 0; n < 4; ++n) acc[m][n] = {0.f, 0.f, 0.f, 0.f};

  bf16x8 afr[4], bfr[4];

#define PH_READ_B(base, KSL) { _Pragma("unroll") \
    for (int n = 0; n < 4; ++n) \
      bfr[n] = *(const bf16x8*)((base) + bBase + (KSL)*16384 + n*512); }
#define PH_READ_A(base, KSL, M0) { _Pragma("unroll") \
    for (int m = 0; m < 4; ++m) \
      afr[m] = *(const bf16x8*)((base) + aBase + (KSL)*16384 + ((M0)+m)*512); }
#define PH_MFMA(R0) { __builtin_amdgcn_s_setprio(1); _Pragma("unroll") \
    for (int m = 0; m < 4; ++m){ _Pragma("unroll") \
      for (int n = 0; n < 4; ++n) \
        acc[(R0)+m][n] = __builtin_amdgcn_mfma_f32_16x16x32_bf16(afr[m], bfr[n], acc[(R0)+m][n], 0, 0, 0); } \
    __builtin_amdgcn_s_setprio(0); }

  const int T = Kdim >> 6;

  // prologue: all 4 chunks of tile 0 (8 loads); wait chunks 0,1
  stage(0, 0, 0); stage(0, 1, 0); stage(0, 2, 0); stage(0, 3, 0);
  asm volatile("s_waitcnt vmcnt(4)" ::: "memory");
  __builtin_amdgcn_s_barrier();

  for (int t = 0; t < T - 1; ++t){
    const int b = t & 1;
    const unsigned char* base = lds + b * 65536;
    // phase 0: ksl0, acc rows 0-3
    PH_READ_B(base, 0); PH_READ_A(base, 0, 0);
    stage(t + 1, 0, b ^ 1);
    __builtin_amdgcn_s_barrier();
    PH_MFMA(0);
    __builtin_amdgcn_s_barrier();
    // phase 1: ksl0, acc rows 4-7
    PH_READ_A(base, 0, 4);
    stage(t + 1, 1, b ^ 1);
    asm volatile("s_waitcnt vmcnt(4)" ::: "memory");   // chunks 2,3 of t landed
    __builtin_amdgcn_s_barrier();
    PH_MFMA(4);
    __builtin_amdgcn_s_barrier();
    // phase 2: ksl1, acc rows 0-3
    PH_READ_B(base, 1); PH_READ_A(base, 1, 0);
    stage(t + 1, 2, b ^ 1);
    __builtin_amdgcn_s_barrier();
    PH_MFMA(0);
    __builtin_amdgcn_s_barrier();
    // phase 3: ksl1, acc rows 4-7
    PH_READ_A(base, 1, 4);
    stage(t + 1, 3, b ^ 1);
    asm volatile("s_waitcnt vmcnt(4)" ::: "memory");   // chunks 0,1 of t+1 landed
    __builtin_amdgcn_s_barrier();
    PH_MFMA(4);
    __builtin_amdgcn_s_barrier();
  }
  { // peeled last tile: no staging; drain remaining chunks at phase 1
    const unsigned char* base = lds + ((T - 1) & 1) * 65536;
    PH_READ_B(base, 0); PH_READ_A(base, 0, 0);
    __builtin_amdgcn_s_barrier();
    PH_MFMA(0);
    __builtin_amdgcn_s_barrier();
    PH_READ_A(base, 0, 4);
    asm volatile("s_waitcnt vmcnt(0)" ::: "memory");   // chunks 2,3 landed
    __builtin_amdgcn_s_barrier();
    PH_MFMA(4);
    __builtin_amdgcn_s_barrier();
    PH_READ_B(base, 1); PH_READ_A(base, 1, 0);
    PH_MFMA(0);
    PH_READ_A(base, 1, 4);
    PH_MFMA(4);
  }
#undef PH_READ_B
#undef PH_READ_A
#undef PH_MFMA

  __builtin_amdgcn_s_barrier();

  if (EPI == 1){
    // f32 out + residual
    #pragma unroll
    for (int n = 0; n < 4; ++n){
      int col = nbase + wn * 64 + n * 16 + l15;
      float bb = bias[col];
      #pragma unroll
      for (int m = 0; m < 8; ++m){
        #pragma unroll
        for (int j = 0; j < 4; ++j){
          int row = mbase + wm * 128 + m * 16 + kg * 4 + j;
          if (row < Mdim){
            size_t o = (size_t)row * Ndim + col;
            ((float*)outp)[o] = acc[m][n][j] + bb + resid[o];
          }
        }
      }
    }
  } else {
    // bf16 out, coalesced via LDS: 2 chunks of 128 rows x 256 cols
    ushort_t* cbuf = (ushort_t*)lds;
    for (int c = 0; c < 2; ++c){
      if (wm == c){
        #pragma unroll
        for (int n = 0; n < 4; ++n){
          int col = nbase + wn * 64 + n * 16 + l15;
          float bb = bias[col];
          #pragma unroll
          for (int m = 0; m < 8; ++m){
            #pragma unroll
            for (int j = 0; j < 4; ++j)
              cbuf[(m * 16 + kg * 4 + j) * 256 + wn * 64 + n * 16 + l15] =
                  f2bf(acc[m][n][j] + bb);
          }
        }
      }
      __syncthreads();
      #pragma unroll
      for (int it = 0; it < 8; ++it){
        int r = it * 16 + (tid >> 5);          // 0..127
        int cb = (tid & 31) * 8;               // col elems 0..248
        int grow = mbase + c * 128 + r;
        if (grow < Mdim)
          *(uint4*)((ushort_t*)outp + (size_t)grow * Ndim + nbase + cb) =
              *(const uint4*)(cbuf + r * 256 + cb);
      }
      __syncthreads();
    }
  }
}

// ---------------- per-token attention over L=3 keys --------------------------
__global__ __launch_bounds__(256) void k_attn(const ushort_t* __restrict__ Qb,
    const float* __restrict__ kn, const float* __restrict__ vv,
    const float* __restrict__ qnw, ushort_t* __restrict__ Ob){
  int wid = threadIdx.x >> 6, lane = threadIdx.x & 63;
  int m = blockIdx.x * 4 + wid;           // grid 2640 * 4 waves = 10560 exact
  float qw = qnw[lane];
  const ushort_t* qrow = Qb + (size_t)m * 1024;
  ushort_t* orow = Ob + (size_t)m * 1024;
  for (int h = 0; h < 16; ++h){
    int ib = h * 64 + lane;
    float q = bf2f(qrow[ib]);
    float ss = wave_sum(q * q);
    float qn = q * rsqrtf(ss * (1.f/64.f) + 1e-6f) * qw;
    float s0 = wave_sum(qn * kn[ib]) * 0.125f;
    float s1 = wave_sum(qn * kn[1024 + ib]) * 0.125f;
    float s2 = wave_sum(qn * kn[2048 + ib]) * 0.125f;
    float mx = fmaxf(s0, fmaxf(s1, s2));
    float e0 = __expf(s0 - mx), e1 = __expf(s1 - mx), e2 = __expf(s2 - mx);
    float inv = 1.f / (e0 + e1 + e2);
    float o = (e0 * vv[ib] + e1 * vv[1024 + ib] + e2 * vv[2048 + ib]) * inv;
    orow[ib] = f2bf(o);
  }
}

extern "C" void kernel_launch(void* const* d_in, const int* in_sizes, int n_in,
                              void* d_out, int out_size, void* d_ws, size_t ws_size,
                              hipStream_t stream){
  const float* x    = (const float*)d_in[0];
  const float* cond = (const float*)d_in[1];
  const float* mew1 = (const float*)d_in[2];
  const float* meb1 = (const float*)d_in[3];
  const float* mew2 = (const float*)d_in[4];
  const float* meb2 = (const float*)d_in[5];
  const float* qw   = (const float*)d_in[6];
  const float* qb   = (const float*)d_in[7];
  const float* kvw  = (const float*)d_in[8];
  const float* kvb  = (const float*)d_in[9];
  const float* qnw  = (const float*)d_in[10];
  const float* knw  = (const float*)d_in[11];
  const float* ow   = (const float*)d_in[12];
  const float* ob   = (const float*)d_in[13];

  char* ws = (char*)d_ws;
  float*    emb    = (float*)(ws + 0);          // 16x512 f32
  float*    kvpart = (float*)(ws + 32768);      // 16x6144 f32
  float*    kn     = (float*)(ws + 425984);     // 3x1024 f32
  float*    vv     = (float*)(ws + 438272);     // 3x1024 f32
  ushort_t* qwt    = (ushort_t*)(ws + 450560);  // [1024][3072] bf16
  ushort_t* owt    = (ushort_t*)(ws + 6742016); // [3072][1024] bf16
  ushort_t* Qbuf   = (ushort_t*)(ws + 13033472);// [10560][1024] bf16
  ushort_t* Obuf   = (ushort_t*)(ws + 34660352);// [10560][1024] bf16

  // xb (bf16 x) lives in d_out's 130MB region: only needed until the Q-GEMM;
  // the final GEMM fully overwrites d_out afterwards. No extra ws needed.
  ushort_t* xb = (ushort_t*)d_out;

  k_pre<<<1, 1024, 0, stream>>>(cond, mew1, meb1, mew2, meb2, emb);
  k_kv<<<384, 256, 0, stream>>>(emb, kvw, kvpart);
  k_knorm<<<1, 256, 0, stream>>>(kvpart, kvb, knw, kn, vv);
  k_tconv<<<3072, 256, 0, stream>>>(qw, qwt, 3072, 1024);
  k_tconv<<<3072, 256, 0, stream>>>(ow, owt, 1024, 3072);
  k_xconv<<<2048, 256, 0, stream>>>(x, xb, (TOK * CIMG) / 4);
  gemm8p<0><<<42 * 4, 512, 0, stream>>>(xb, qwt, TOK, CIMG, KHD, qb, nullptr, Qbuf);
  k_attn<<<2640, 256, 0, stream>>>(Qbuf, kn, vv, qnw, Obuf);
  gemm8p<1><<<42 * 12, 512, 0, stream>>>(Obuf, owt, TOK, KHD, CIMG, ob, x, d_out);
}

// Round 7
// 467.373 us; speedup vs baseline: 1.1862x; 1.1862x over previous
//
#include <hip/hip_runtime.h>

#define TOK  10560
#define CIMG 3072
#define KHD  1024

typedef unsigned short ushort_t;
typedef unsigned int u32;
using bf16x8 = __attribute__((ext_vector_type(8))) __bf16;
using f32x4  = __attribute__((ext_vector_type(4))) float;

#define GLD_LDS16(gp, lp) __builtin_amdgcn_global_load_lds( \
    (const __attribute__((address_space(1))) u32*)(gp), \
    (__attribute__((address_space(3))) u32*)(lp), 16, 0, 0)

static __device__ __forceinline__ unsigned short f2bf(float f){
  union { float f; unsigned u; } x; x.f = f;
  unsigned r = x.u + 0x7fffu + ((x.u >> 16) & 1u);
  return (unsigned short)(r >> 16);
}
static __device__ __forceinline__ float bf2f(unsigned short u){
  union { unsigned u; float f; } x; x.u = ((unsigned)u) << 16; return x.f;
}
static __device__ __forceinline__ float wave_sum(float v){
  #pragma unroll
  for (int off = 32; off > 0; off >>= 1) v += __shfl_xor(v, off, 64);
  return v;
}

// ---------------- conditioning MLP: emb rows 72..87 (cond rows 64..79) -------
__global__ void k_pre(const float* __restrict__ cond,
                      const float* __restrict__ w1, const float* __restrict__ b1,
                      const float* __restrict__ w2, const float* __restrict__ b2,
                      float* __restrict__ emb){
  __shared__ float cs[16][16];
  __shared__ float h1[16][512];
  int t = threadIdx.x;
  if (t < 256) cs[t >> 4][t & 15] = cond[(64 + (t >> 4)) * 16 + (t & 15)];
  __syncthreads();
  #pragma unroll
  for (int i = 0; i < 8; ++i){
    int idx = t + i * 1024; int r = idx >> 9, c = idx & 511;
    float s = b1[c];
    #pragma unroll
    for (int j = 0; j < 16; ++j) s += cs[r][j] * w1[j * 512 + c];
    h1[r][c] = s / (1.f + __expf(-s));   // silu
  }
  __syncthreads();
  #pragma unroll
  for (int i = 0; i < 8; ++i){
    int idx = t + i * 1024; int r = idx >> 9, c = idx & 511;
    float e = b2[c];
    for (int j = 0; j < 512; ++j) e += h1[r][j] * w2[j * 512 + c];
    emb[idx] = e;
  }
}

// ---------------- kv = mf @ kv_w, split-K partials (deterministic) ----------
__global__ __launch_bounds__(256) void k_kv(const float* __restrict__ emb,
                                            const float* __restrict__ kvw,
                                            float* __restrict__ part){
  int bl = blockIdx.x;                 // 3 l * 8 ntile * 16 kchunk = 384
  int l = bl / 128, rem = bl % 128, nt = rem / 16, kc = rem % 16;
  int n = nt * 256 + threadIdx.x;
  const float* e = emb + 2048 * l + kc * 256;   // mf[l][r] = emb[2048l + r]
  const float* w = kvw + (size_t)(kc * 256) * 2048 + n;
  float acc = 0.f;
  for (int r = 0; r < 256; ++r) acc += e[r] * w[(size_t)r * 2048];
  part[kc * 6144 + l * 2048 + n] = acc;
}

// ---------------- reduce partials, bias, k-RMSNorm ---------------------------
__global__ void k_knorm(const float* __restrict__ part, const float* __restrict__ kvb,
                        const float* __restrict__ knw, float* __restrict__ kn,
                        float* __restrict__ vv){
  int wid = threadIdx.x >> 6, lane = threadIdx.x & 63;
  for (int i = 0; i < 12; ++i){
    int g = wid * 12 + i;               // 0..47 = (l,h)
    int l = g >> 4, h = g & 15;
    int ik = l * 2048 + h * 64 + lane;
    float kk = kvb[h * 64 + lane];
    float v  = kvb[1024 + h * 64 + lane];
    for (int p = 0; p < 16; ++p){ kk += part[p * 6144 + ik]; v += part[p * 6144 + ik + 1024]; }
    float ss = wave_sum(kk * kk);
    kn[l * 1024 + h * 64 + lane] = kk * rsqrtf(ss * (1.f/64.f) + 1e-6f) * knw[lane];
    vv[l * 1024 + h * 64 + lane] = v;
  }
}

// ---------------- transpose + f32->bf16 weight convert: dst[C][R] ------------
__global__ __launch_bounds__(256) void k_tconv(const float* __restrict__ src,
                                               ushort_t* __restrict__ dst,
                                               int R, int C){
  __shared__ float tile[32][33];
  int nTr = R >> 5;
  int tr = blockIdx.x % nTr, tc = blockIdx.x / nTr;
  int r0 = tr * 32, c0 = tc * 32, t = threadIdx.x;
  #pragma unroll
  for (int i = 0; i < 4; ++i){
    int idx = t + i * 256; int r = idx >> 5, c = idx & 31;
    tile[r][c] = src[(size_t)(r0 + r) * C + c0 + c];
  }
  __syncthreads();
  #pragma unroll
  for (int i = 0; i < 4; ++i){
    int idx = t + i * 256; int rr = idx >> 5, cc = idx & 31;
    dst[(size_t)(c0 + rr) * R + r0 + cc] = f2bf(tile[cc][rr]);
  }
}

// ---------------- x f32 -> bf16 streaming convert ----------------------------
__global__ __launch_bounds__(256) void k_xconv(const float* __restrict__ x,
                                               ushort_t* __restrict__ xb, int n4){
  for (int i = blockIdx.x * 256 + threadIdx.x; i < n4; i += gridDim.x * 256){
    float4 v = ((const float4*)x)[i];
    ushort4 o;
    o.x = f2bf(v.x); o.y = f2bf(v.y); o.z = f2bf(v.z); o.w = f2bf(v.w);
    ((ushort4*)xb)[i] = o;
  }
}

// ============ 256x256 bf16 MFMA GEMM, m201-style 8-phase schedule ============
// (unchanged from round 5 — passing; used only for the Q projection)
template<int EPI>
__global__ __launch_bounds__(512, 2) void gemm8p(
    const ushort_t* __restrict__ A, const ushort_t* __restrict__ Bt,
    int Mdim, int Kdim, int Ndim,
    const float* __restrict__ bias, const float* __restrict__ resid,
    void* __restrict__ outp){
  __shared__ __align__(16) unsigned char lds[131072];
  const int tid = threadIdx.x;
  const int lane = tid & 63, wid = tid >> 6;
  const int wm = wid >> 2, wn = wid & 3;     // 2 x 4 waves -> per-wave 128x64
  const int l15 = lane & 15, kg = lane >> 4;
  const int ntiles = Ndim >> 8;

  int bid = blockIdx.x;
  const int cpx = gridDim.x >> 3;
  bid = (bid & 7) * cpx + (bid >> 3);
  const int mt = bid / ntiles, nt = bid % ntiles;
  const int mbase = mt << 8, nbase = nt << 8;

  const int sr  = tid >> 1;                       // 0..255
  const int skh = (tid & 1) ^ ((sr >> 2) & 1);    // inverse swizzle on source
  int arow = mbase + sr; if (arow >= Mdim) arow = Mdim - 1;
  const ushort_t* gA = A  + (size_t)arow * Kdim + skh * 8;
  const ushort_t* gB = Bt + (size_t)(nbase + sr) * Kdim + skh * 8;
  const int wofs = wid * 1024;

  auto stage = [&](int t, int c, int b){
    const int gk = t * 64 + c * 16;
    unsigned char* dst = lds + b * 65536 + c * 8192 + wofs;
    GLD_LDS16(gA + gk, dst);
    GLD_LDS16(gB + gk, dst + 32768);
  };

  const int arl = wm * 128 + l15;
  const int brl = wn * 64 + l15;
  const int kh  = ((kg & 1) ^ ((l15 >> 2) & 1)) * 16;
  const unsigned aBase = (unsigned)((kg >> 1) * 8192 + arl * 32 + kh);
  const unsigned bBase = (unsigned)(32768 + (kg >> 1) * 8192 + brl * 32 + kh);

  f32x4 acc[8][4];
  #pragma unroll
  for (int m = 0; m < 8; ++m)
    #pragma unroll
    for (int n = 0; n < 4; ++n) acc[m][n] = {0.f, 0.f, 0.f, 0.f};

  bf16x8 afr[4], bfr[4];

#define PH_READ_B(base, KSL) { _Pragma("unroll") \
    for (int n = 0; n < 4; ++n) \
      bfr[n] = *(const bf16x8*)((base) + bBase + (KSL)*16384 + n*512); }
#define PH_READ_A(base, KSL, M0) { _Pragma("unroll") \
    for (int m = 0; m < 4; ++m) \
      afr[m] = *(const bf16x8*)((base) + aBase + (KSL)*16384 + ((M0)+m)*512); }
#define PH_MFMA(R0) { __builtin_amdgcn_s_setprio(1); _Pragma("unroll") \
    for (int m = 0; m < 4; ++m){ _Pragma("unroll") \
      for (int n = 0; n < 4; ++n) \
        acc[(R0)+m][n] = __builtin_amdgcn_mfma_f32_16x16x32_bf16(afr[m], bfr[n], acc[(R0)+m][n], 0, 0, 0); } \
    __builtin_amdgcn_s_setprio(0); }

  const int T = Kdim >> 6;

  stage(0, 0, 0); stage(0, 1, 0); stage(0, 2, 0); stage(0, 3, 0);
  asm volatile("s_waitcnt vmcnt(4)" ::: "memory");
  __builtin_amdgcn_s_barrier();

  for (int t = 0; t < T - 1; ++t){
    const int b = t & 1;
    const unsigned char* base = lds + b * 65536;
    PH_READ_B(base, 0); PH_READ_A(base, 0, 0);
    stage(t + 1, 0, b ^ 1);
    __builtin_amdgcn_s_barrier();
    PH_MFMA(0);
    __builtin_amdgcn_s_barrier();
    PH_READ_A(base, 0, 4);
    stage(t + 1, 1, b ^ 1);
    asm volatile("s_waitcnt vmcnt(4)" ::: "memory");
    __builtin_amdgcn_s_barrier();
    PH_MFMA(4);
    __builtin_amdgcn_s_barrier();
    PH_READ_B(base, 1); PH_READ_A(base, 1, 0);
    stage(t + 1, 2, b ^ 1);
    __builtin_amdgcn_s_barrier();
    PH_MFMA(0);
    __builtin_amdgcn_s_barrier();
    PH_READ_A(base, 1, 4);
    stage(t + 1, 3, b ^ 1);
    asm volatile("s_waitcnt vmcnt(4)" ::: "memory");
    __builtin_amdgcn_s_barrier();
    PH_MFMA(4);
    __builtin_amdgcn_s_barrier();
  }
  {
    const unsigned char* base = lds + ((T - 1) & 1) * 65536;
    PH_READ_B(base, 0); PH_READ_A(base, 0, 0);
    __builtin_amdgcn_s_barrier();
    PH_MFMA(0);
    __builtin_amdgcn_s_barrier();
    PH_READ_A(base, 0, 4);
    asm volatile("s_waitcnt vmcnt(0)" ::: "memory");
    __builtin_amdgcn_s_barrier();
    PH_MFMA(4);
    __builtin_amdgcn_s_barrier();
    PH_READ_B(base, 1); PH_READ_A(base, 1, 0);
    PH_MFMA(0);
    PH_READ_A(base, 1, 4);
    PH_MFMA(4);
  }
#undef PH_READ_B
#undef PH_READ_A
#undef PH_MFMA

  __builtin_amdgcn_s_barrier();

  if (EPI == 1){
    #pragma unroll
    for (int n = 0; n < 4; ++n){
      int col = nbase + wn * 64 + n * 16 + l15;
      float bb = bias[col];
      #pragma unroll
      for (int m = 0; m < 8; ++m){
        #pragma unroll
        for (int j = 0; j < 4; ++j){
          int row = mbase + wm * 128 + m * 16 + kg * 4 + j;
          if (row < Mdim){
            size_t o = (size_t)row * Ndim + col;
            ((float*)outp)[o] = acc[m][n][j] + bb + resid[o];
          }
        }
      }
    }
  } else {
    ushort_t* cbuf = (ushort_t*)lds;
    for (int c = 0; c < 2; ++c){
      if (wm == c){
        #pragma unroll
        for (int n = 0; n < 4; ++n){
          int col = nbase + wn * 64 + n * 16 + l15;
          float bb = bias[col];
          #pragma unroll
          for (int m = 0; m < 8; ++m){
            #pragma unroll
            for (int j = 0; j < 4; ++j)
              cbuf[(m * 16 + kg * 4 + j) * 256 + wn * 64 + n * 16 + l15] =
                  f2bf(acc[m][n][j] + bb);
          }
        }
      }
      __syncthreads();
      #pragma unroll
      for (int it = 0; it < 8; ++it){
        int r = it * 16 + (tid >> 5);
        int cb = (tid & 31) * 8;
        int grow = mbase + c * 128 + r;
        if (grow < Mdim)
          *(uint4*)((ushort_t*)outp + (size_t)grow * Ndim + nbase + cb) =
              *(const uint4*)(cbuf + r * 256 + cb);
      }
      __syncthreads();
    }
  }
}

// ------- attention coefficients: a[t, h*3+l] = softmax_l(qn.kn/8) ------------
__global__ __launch_bounds__(256) void k_attn(const ushort_t* __restrict__ Qb,
    const float* __restrict__ kn, const float* __restrict__ qnw,
    float* __restrict__ acoef){
  int wid = threadIdx.x >> 6, lane = threadIdx.x & 63;
  int m = blockIdx.x * 4 + wid;           // grid 2640 * 4 waves = 10560 exact
  float qw = qnw[lane];
  const ushort_t* qrow = Qb + (size_t)m * 1024;
  for (int h = 0; h < 16; ++h){
    int ib = h * 64 + lane;
    float q = bf2f(qrow[ib]);
    float ss = wave_sum(q * q);
    float qn = q * rsqrtf(ss * (1.f/64.f) + 1e-6f) * qw;
    float s0 = wave_sum(qn * kn[ib]) * 0.125f;
    float s1 = wave_sum(qn * kn[1024 + ib]) * 0.125f;
    float s2 = wave_sum(qn * kn[2048 + ib]) * 0.125f;
    float mx = fmaxf(s0, fmaxf(s1, s2));
    float e0 = __expf(s0 - mx), e1 = __expf(s1 - mx), e2 = __expf(s2 - mx);
    float inv = 1.f / (e0 + e1 + e2);
    if (lane < 3){
      float e = (lane == 0) ? e0 : (lane == 1) ? e1 : e2;
      acoef[(size_t)m * 48 + h * 3 + lane] = e * inv;
    }
  }
}

// ------- U[h*3+l][c] = sum_d v[l,h,d] * out_w[h*64+d][c]  (48 x 3072, f32) ---
__global__ __launch_bounds__(512) void k_uv(const float* __restrict__ vv,
    const float* __restrict__ ow, float* __restrict__ U){
  int b = blockIdx.x;             // 48 i * 6 cchunk = 288
  int i = b / 6, cc = b % 6;
  int h = i / 3, l = i % 3;
  int c = cc * 512 + threadIdx.x;
  const float* vp = vv + l * 1024 + h * 64;
  const float* wp = ow + (size_t)(h * 64) * 3072 + c;
  float acc = 0.f;
  #pragma unroll
  for (int d = 0; d < 64; ++d) acc += vp[d] * wp[(size_t)d * 3072];
  U[(size_t)i * 3072 + c] = acc;
}

// ------- out = x + out_b + acoef @ U   (rank-48 f32 update) ------------------
// grid: 88 mslices * 12 cchunks; block 256 threads, one col per thread.
__global__ __launch_bounds__(256) void k_rank48(const float* __restrict__ x,
    const float* __restrict__ acoef, const float* __restrict__ U,
    const float* __restrict__ ob, float* __restrict__ out){
  __shared__ __align__(16) float as[120][48];
  const int tid = threadIdx.x;
  const int cc = blockIdx.x % 12, ms = blockIdx.x / 12;
  const int c = cc * 256 + tid;
  const int t0 = ms * 120;

  // a rows for this slice: 120*48 = 5760 f32, coalesced
  for (int idx = tid; idx < 5760; idx += 256)
    ((float*)as)[idx] = acoef[(size_t)t0 * 48 + idx];

  // U column chunk held in registers (constant across rows)
  float ur[48];
  #pragma unroll
  for (int i = 0; i < 48; ++i) ur[i] = U[(size_t)i * 3072 + c];
  float bb = ob[c];
  __syncthreads();

  for (int r = 0; r < 120; ++r){
    const size_t o = (size_t)(t0 + r) * 3072 + c;
    float acc = x[o] + bb;
    const f32x4* ap = (const f32x4*)as[r];
    #pragma unroll
    for (int k = 0; k < 12; ++k){
      f32x4 a4 = ap[k];              // LDS broadcast (same addr all lanes)
      acc += a4[0] * ur[4*k] + a4[1] * ur[4*k+1]
           + a4[2] * ur[4*k+2] + a4[3] * ur[4*k+3];
    }
    out[o] = acc;
  }
}

extern "C" void kernel_launch(void* const* d_in, const int* in_sizes, int n_in,
                              void* d_out, int out_size, void* d_ws, size_t ws_size,
                              hipStream_t stream){
  const float* x    = (const float*)d_in[0];
  const float* cond = (const float*)d_in[1];
  const float* mew1 = (const float*)d_in[2];
  const float* meb1 = (const float*)d_in[3];
  const float* mew2 = (const float*)d_in[4];
  const float* meb2 = (const float*)d_in[5];
  const float* qw   = (const float*)d_in[6];
  const float* qb   = (const float*)d_in[7];
  const float* kvw  = (const float*)d_in[8];
  const float* kvb  = (const float*)d_in[9];
  const float* qnw  = (const float*)d_in[10];
  const float* knw  = (const float*)d_in[11];
  const float* ow   = (const float*)d_in[12];
  const float* ob   = (const float*)d_in[13];

  char* ws = (char*)d_ws;
  float*    emb    = (float*)(ws + 0);          // 16x512 f32
  float*    kvpart = (float*)(ws + 32768);      // 16x6144 f32
  float*    kn     = (float*)(ws + 425984);     // 3x1024 f32
  float*    vv     = (float*)(ws + 438272);     // 3x1024 f32
  ushort_t* qwt    = (ushort_t*)(ws + 450560);  // [1024][3072] bf16
  float*    U      = (float*)(ws + 6742016);    // [48][3072] f32
  float*    acoef  = (float*)(ws + 7331840);    // [10560][48] f32
  ushort_t* Qbuf   = (ushort_t*)(ws + 13033472);// [10560][1024] bf16

  // xb (bf16 x) lives in d_out: needed only until the Q-GEMM; k_rank48
  // fully overwrites d_out at the end of every call.
  ushort_t* xb = (ushort_t*)d_out;

  k_pre<<<1, 1024, 0, stream>>>(cond, mew1, meb1, mew2, meb2, emb);
  k_kv<<<384, 256, 0, stream>>>(emb, kvw, kvpart);
  k_knorm<<<1, 256, 0, stream>>>(kvpart, kvb, knw, kn, vv);
  k_uv<<<288, 512, 0, stream>>>(vv, ow, U);
  k_tconv<<<3072, 256, 0, stream>>>(qw, qwt, 3072, 1024);
  k_xconv<<<2048, 256, 0, stream>>>(x, xb, (TOK * CIMG) / 4);
  gemm8p<0><<<42 * 4, 512, 0, stream>>>(xb, qwt, TOK, CIMG, KHD, qb, nullptr, Qbuf);
  k_attn<<<2640, 256, 0, stream>>>(Qbuf, kn, qnw, acoef);
  k_rank48<<<88 * 12, 256, 0, stream>>>(x, acoef, U, ob, (float*)d_out);
}

// Round 8
// 362.974 us; speedup vs baseline: 1.5274x; 1.2876x over previous
//
#include <hip/hip_runtime.h>

#define TOK  10560
#define CIMG 3072
#define KHD  1024

typedef unsigned short ushort_t;
typedef unsigned int u32;
using bf16x8 = __attribute__((ext_vector_type(8))) __bf16;
using f32x4  = __attribute__((ext_vector_type(4))) float;

#define GLD_LDS16(gp, lp) __builtin_amdgcn_global_load_lds( \
    (const __attribute__((address_space(1))) u32*)(gp), \
    (__attribute__((address_space(3))) u32*)(lp), 16, 0, 0)

static __device__ __forceinline__ unsigned short f2bf(float f){
  union { float f; unsigned u; } x; x.f = f;
  unsigned r = x.u + 0x7fffu + ((x.u >> 16) & 1u);
  return (unsigned short)(r >> 16);
}
static __device__ __forceinline__ float bf2f(unsigned short u){
  union { unsigned u; float f; } x; x.u = ((unsigned)u) << 16; return x.f;
}
static __device__ __forceinline__ float wave_sum(float v){
  #pragma unroll
  for (int off = 32; off > 0; off >>= 1) v += __shfl_xor(v, off, 64);
  return v;
}

// ---------------- conditioning MLP layer 1: h1 = silu(cp@w1+b1), rows 72..87 -
// (cp rows 72..87 == cond rows 64..79). 8 blocks x 256 thr, 4 outputs each.
__global__ __launch_bounds__(256) void k_pre1(const float* __restrict__ cond,
    const float* __restrict__ w1, const float* __restrict__ b1,
    float* __restrict__ h1){
  __shared__ float cs[16][16];
  int t = threadIdx.x;
  if (t < 256) cs[t >> 4][t & 15] = cond[(64 + (t >> 4)) * 16 + (t & 15)];
  __syncthreads();
  #pragma unroll
  for (int i = 0; i < 4; ++i){
    int idx = blockIdx.x * 256 + t + i * 2048;
    int r = idx >> 9, c = idx & 511;
    float s = b1[c];
    #pragma unroll
    for (int j = 0; j < 16; ++j) s += cs[r][j] * w1[j * 512 + c];
    h1[idx] = s / (1.f + __expf(-s));   // silu
  }
}

// ---------------- conditioning MLP layer 2: emb = h1@w2 + b2 -----------------
// 32 blocks x 256 thr, one output each. w2 cols coalesced; h1 row wave-uniform.
__global__ __launch_bounds__(256) void k_pre2(const float* __restrict__ h1,
    const float* __restrict__ w2, const float* __restrict__ b2,
    float* __restrict__ emb){
  int idx = blockIdx.x * 256 + threadIdx.x;
  int r = idx >> 9, c = idx & 511;
  const float* hp = h1 + r * 512;
  const float* wp = w2 + c;
  float acc = b2[c];
  #pragma unroll 8
  for (int j = 0; j < 512; ++j) acc += hp[j] * wp[(size_t)j * 512];
  emb[idx] = acc;
}

// ---------------- kv = mf @ kv_w, split-K partials (deterministic) ----------
__global__ __launch_bounds__(256) void k_kv(const float* __restrict__ emb,
                                            const float* __restrict__ kvw,
                                            float* __restrict__ part){
  int bl = blockIdx.x;                 // 3 l * 8 ntile * 16 kchunk = 384
  int l = bl / 128, rem = bl % 128, nt = rem / 16, kc = rem % 16;
  int n = nt * 256 + threadIdx.x;
  const float* e = emb + 2048 * l + kc * 256;   // mf[l][r] = emb[2048l + r]
  const float* w = kvw + (size_t)(kc * 256) * 2048 + n;
  float acc = 0.f;
  for (int r = 0; r < 256; ++r) acc += e[r] * w[(size_t)r * 2048];
  part[kc * 6144 + l * 2048 + n] = acc;
}

// ---------------- reduce partials, bias, k-RMSNorm ---------------------------
__global__ void k_knorm(const float* __restrict__ part, const float* __restrict__ kvb,
                        const float* __restrict__ knw, float* __restrict__ kn,
                        float* __restrict__ vv){
  int wid = threadIdx.x >> 6, lane = threadIdx.x & 63;
  for (int i = 0; i < 12; ++i){
    int g = wid * 12 + i;               // 0..47 = (l,h)
    int l = g >> 4, h = g & 15;
    int ik = l * 2048 + h * 64 + lane;
    float kk = kvb[h * 64 + lane];
    float v  = kvb[1024 + h * 64 + lane];
    for (int p = 0; p < 16; ++p){ kk += part[p * 6144 + ik]; v += part[p * 6144 + ik + 1024]; }
    float ss = wave_sum(kk * kk);
    kn[l * 1024 + h * 64 + lane] = kk * rsqrtf(ss * (1.f/64.f) + 1e-6f) * knw[lane];
    vv[l * 1024 + h * 64 + lane] = v;
  }
}

// ---------------- transpose + f32->bf16 weight convert: dst[C][R] ------------
__global__ __launch_bounds__(256) void k_tconv(const float* __restrict__ src,
                                               ushort_t* __restrict__ dst,
                                               int R, int C){
  __shared__ float tile[32][33];
  int nTr = R >> 5;
  int tr = blockIdx.x % nTr, tc = blockIdx.x / nTr;
  int r0 = tr * 32, c0 = tc * 32, t = threadIdx.x;
  #pragma unroll
  for (int i = 0; i < 4; ++i){
    int idx = t + i * 256; int r = idx >> 5, c = idx & 31;
    tile[r][c] = src[(size_t)(r0 + r) * C + c0 + c];
  }
  __syncthreads();
  #pragma unroll
  for (int i = 0; i < 4; ++i){
    int idx = t + i * 256; int rr = idx >> 5, cc = idx & 31;
    dst[(size_t)(c0 + rr) * R + r0 + cc] = f2bf(tile[cc][rr]);
  }
}

// ---------------- x f32 -> bf16 streaming convert ----------------------------
__global__ __launch_bounds__(256) void k_xconv(const float* __restrict__ x,
                                               ushort_t* __restrict__ xb, int n4){
  for (int i = blockIdx.x * 256 + threadIdx.x; i < n4; i += gridDim.x * 256){
    float4 v = ((const float4*)x)[i];
    ushort4 o;
    o.x = f2bf(v.x); o.y = f2bf(v.y); o.z = f2bf(v.z); o.w = f2bf(v.w);
    ((ushort4*)xb)[i] = o;
  }
}

// ============ 256x256 bf16 MFMA GEMM, m201-style 8-phase schedule ============
// (unchanged — passing; used only for the Q projection)
template<int EPI>
__global__ __launch_bounds__(512, 2) void gemm8p(
    const ushort_t* __restrict__ A, const ushort_t* __restrict__ Bt,
    int Mdim, int Kdim, int Ndim,
    const float* __restrict__ bias, const float* __restrict__ resid,
    void* __restrict__ outp){
  __shared__ __align__(16) unsigned char lds[131072];
  const int tid = threadIdx.x;
  const int lane = tid & 63, wid = tid >> 6;
  const int wm = wid >> 2, wn = wid & 3;     // 2 x 4 waves -> per-wave 128x64
  const int l15 = lane & 15, kg = lane >> 4;
  const int ntiles = Ndim >> 8;

  int bid = blockIdx.x;
  const int cpx = gridDim.x >> 3;
  bid = (bid & 7) * cpx + (bid >> 3);
  const int mt = bid / ntiles, nt = bid % ntiles;
  const int mbase = mt << 8, nbase = nt << 8;

  const int sr  = tid >> 1;                       // 0..255
  const int skh = (tid & 1) ^ ((sr >> 2) & 1);    // inverse swizzle on source
  int arow = mbase + sr; if (arow >= Mdim) arow = Mdim - 1;
  const ushort_t* gA = A  + (size_t)arow * Kdim + skh * 8;
  const ushort_t* gB = Bt + (size_t)(nbase + sr) * Kdim + skh * 8;
  const int wofs = wid * 1024;

  auto stage = [&](int t, int c, int b){
    const int gk = t * 64 + c * 16;
    unsigned char* dst = lds + b * 65536 + c * 8192 + wofs;
    GLD_LDS16(gA + gk, dst);
    GLD_LDS16(gB + gk, dst + 32768);
  };

  const int arl = wm * 128 + l15;
  const int brl = wn * 64 + l15;
  const int kh  = ((kg & 1) ^ ((l15 >> 2) & 1)) * 16;
  const unsigned aBase = (unsigned)((kg >> 1) * 8192 + arl * 32 + kh);
  const unsigned bBase = (unsigned)(32768 + (kg >> 1) * 8192 + brl * 32 + kh);

  f32x4 acc[8][4];
  #pragma unroll
  for (int m = 0; m < 8; ++m)
    #pragma unroll
    for (int n = 0; n < 4; ++n) acc[m][n] = {0.f, 0.f, 0.f, 0.f};

  bf16x8 afr[4], bfr[4];

#define PH_READ_B(base, KSL) { _Pragma("unroll") \
    for (int n = 0; n < 4; ++n) \
      bfr[n] = *(const bf16x8*)((base) + bBase + (KSL)*16384 + n*512); }
#define PH_READ_A(base, KSL, M0) { _Pragma("unroll") \
    for (int m = 0; m < 4; ++m) \
      afr[m] = *(const bf16x8*)((base) + aBase + (KSL)*16384 + ((M0)+m)*512); }
#define PH_MFMA(R0) { __builtin_amdgcn_s_setprio(1); _Pragma("unroll") \
    for (int m = 0; m < 4; ++m){ _Pragma("unroll") \
      for (int n = 0; n < 4; ++n) \
        acc[(R0)+m][n] = __builtin_amdgcn_mfma_f32_16x16x32_bf16(afr[m], bfr[n], acc[(R0)+m][n], 0, 0, 0); } \
    __builtin_amdgcn_s_setprio(0); }

  const int T = Kdim >> 6;

  stage(0, 0, 0); stage(0, 1, 0); stage(0, 2, 0); stage(0, 3, 0);
  asm volatile("s_waitcnt vmcnt(4)" ::: "memory");
  __builtin_amdgcn_s_barrier();

  for (int t = 0; t < T - 1; ++t){
    const int b = t & 1;
    const unsigned char* base = lds + b * 65536;
    PH_READ_B(base, 0); PH_READ_A(base, 0, 0);
    stage(t + 1, 0, b ^ 1);
    __builtin_amdgcn_s_barrier();
    PH_MFMA(0);
    __builtin_amdgcn_s_barrier();
    PH_READ_A(base, 0, 4);
    stage(t + 1, 1, b ^ 1);
    asm volatile("s_waitcnt vmcnt(4)" ::: "memory");
    __builtin_amdgcn_s_barrier();
    PH_MFMA(4);
    __builtin_amdgcn_s_barrier();
    PH_READ_B(base, 1); PH_READ_A(base, 1, 0);
    stage(t + 1, 2, b ^ 1);
    __builtin_amdgcn_s_barrier();
    PH_MFMA(0);
    __builtin_amdgcn_s_barrier();
    PH_READ_A(base, 1, 4);
    stage(t + 1, 3, b ^ 1);
    asm volatile("s_waitcnt vmcnt(4)" ::: "memory");
    __builtin_amdgcn_s_barrier();
    PH_MFMA(4);
    __builtin_amdgcn_s_barrier();
  }
  {
    const unsigned char* base = lds + ((T - 1) & 1) * 65536;
    PH_READ_B(base, 0); PH_READ_A(base, 0, 0);
    __builtin_amdgcn_s_barrier();
    PH_MFMA(0);
    __builtin_amdgcn_s_barrier();
    PH_READ_A(base, 0, 4);
    asm volatile("s_waitcnt vmcnt(0)" ::: "memory");
    __builtin_amdgcn_s_barrier();
    PH_MFMA(4);
    __builtin_amdgcn_s_barrier();
    PH_READ_B(base, 1); PH_READ_A(base, 1, 0);
    PH_MFMA(0);
    PH_READ_A(base, 1, 4);
    PH_MFMA(4);
  }
#undef PH_READ_B
#undef PH_READ_A
#undef PH_MFMA

  __builtin_amdgcn_s_barrier();

  if (EPI == 1){
    #pragma unroll
    for (int n = 0; n < 4; ++n){
      int col = nbase + wn * 64 + n * 16 + l15;
      float bb = bias[col];
      #pragma unroll
      for (int m = 0; m < 8; ++m){
        #pragma unroll
        for (int j = 0; j < 4; ++j){
          int row = mbase + wm * 128 + m * 16 + kg * 4 + j;
          if (row < Mdim){
            size_t o = (size_t)row * Ndim + col;
            ((float*)outp)[o] = acc[m][n][j] + bb + resid[o];
          }
        }
      }
    }
  } else {
    ushort_t* cbuf = (ushort_t*)lds;
    for (int c = 0; c < 2; ++c){
      if (wm == c){
        #pragma unroll
        for (int n = 0; n < 4; ++n){
          int col = nbase + wn * 64 + n * 16 + l15;
          float bb = bias[col];
          #pragma unroll
          for (int m = 0; m < 8; ++m){
            #pragma unroll
            for (int j = 0; j < 4; ++j)
              cbuf[(m * 16 + kg * 4 + j) * 256 + wn * 64 + n * 16 + l15] =
                  f2bf(acc[m][n][j] + bb);
          }
        }
      }
      __syncthreads();
      #pragma unroll
      for (int it = 0; it < 8; ++it){
        int r = it * 16 + (tid >> 5);
        int cb = (tid & 31) * 8;
        int grow = mbase + c * 128 + r;
        if (grow < Mdim)
          *(uint4*)((ushort_t*)outp + (size_t)grow * Ndim + nbase + cb) =
              *(const uint4*)(cbuf + r * 256 + cb);
      }
      __syncthreads();
    }
  }
}

// ------- attention coefficients: a[t, h*3+l] = softmax_l(qn.kn/8) ------------
__global__ __launch_bounds__(256) void k_attn(const ushort_t* __restrict__ Qb,
    const float* __restrict__ kn, const float* __restrict__ qnw,
    float* __restrict__ acoef){
  int wid = threadIdx.x >> 6, lane = threadIdx.x & 63;
  int m = blockIdx.x * 4 + wid;           // grid 2640 * 4 waves = 10560 exact
  float qw = qnw[lane];
  const ushort_t* qrow = Qb + (size_t)m * 1024;
  for (int h = 0; h < 16; ++h){
    int ib = h * 64 + lane;
    float q = bf2f(qrow[ib]);
    float ss = wave_sum(q * q);
    float qn = q * rsqrtf(ss * (1.f/64.f) + 1e-6f) * qw;
    float s0 = wave_sum(qn * kn[ib]) * 0.125f;
    float s1 = wave_sum(qn * kn[1024 + ib]) * 0.125f;
    float s2 = wave_sum(qn * kn[2048 + ib]) * 0.125f;
    float mx = fmaxf(s0, fmaxf(s1, s2));
    float e0 = __expf(s0 - mx), e1 = __expf(s1 - mx), e2 = __expf(s2 - mx);
    float inv = 1.f / (e0 + e1 + e2);
    if (lane < 3){
      float e = (lane == 0) ? e0 : (lane == 1) ? e1 : e2;
      acoef[(size_t)m * 48 + h * 3 + lane] = e * inv;
    }
  }
}

// ------- U[h*3+l][c] = sum_d v[l,h,d] * out_w[h*64+d][c]  (48 x 3072, f32) ---
__global__ __launch_bounds__(512) void k_uv(const float* __restrict__ vv,
    const float* __restrict__ ow, float* __restrict__ U){
  int b = blockIdx.x;             // 48 i * 6 cchunk = 288
  int i = b / 6, cc = b % 6;
  int h = i / 3, l = i % 3;
  int c = cc * 512 + threadIdx.x;
  const float* vp = vv + l * 1024 + h * 64;
  const float* wp = ow + (size_t)(h * 64) * 3072 + c;
  float acc = 0.f;
  #pragma unroll
  for (int d = 0; d < 64; ++d) acc += vp[d] * wp[(size_t)d * 3072];
  U[(size_t)i * 3072 + c] = acc;
}

// ------- out = x + out_b + acoef @ U   (rank-48 f32 update) ------------------
// grid: 88 mslices * 12 cchunks; block 256 threads, one col per thread.
__global__ __launch_bounds__(256) void k_rank48(const float* __restrict__ x,
    const float* __restrict__ acoef, const float* __restrict__ U,
    const float* __restrict__ ob, float* __restrict__ out){
  __shared__ __align__(16) float as[120][48];
  const int tid = threadIdx.x;
  const int cc = blockIdx.x % 12, ms = blockIdx.x / 12;
  const int c = cc * 256 + tid;
  const int t0 = ms * 120;

  // a rows for this slice: 120*48 = 5760 f32, coalesced
  for (int idx = tid; idx < 5760; idx += 256)
    ((float*)as)[idx] = acoef[(size_t)t0 * 48 + idx];

  // U column chunk held in registers (constant across rows)
  float ur[48];
  #pragma unroll
  for (int i = 0; i < 48; ++i) ur[i] = U[(size_t)i * 3072 + c];
  float bb = ob[c];
  __syncthreads();

  for (int r = 0; r < 120; ++r){
    const size_t o = (size_t)(t0 + r) * 3072 + c;
    float acc = x[o] + bb;
    const f32x4* ap = (const f32x4*)as[r];
    #pragma unroll
    for (int k = 0; k < 12; ++k){
      f32x4 a4 = ap[k];              // LDS broadcast (same addr all lanes)
      acc += a4[0] * ur[4*k] + a4[1] * ur[4*k+1]
           + a4[2] * ur[4*k+2] + a4[3] * ur[4*k+3];
    }
    out[o] = acc;
  }
}

extern "C" void kernel_launch(void* const* d_in, const int* in_sizes, int n_in,
                              void* d_out, int out_size, void* d_ws, size_t ws_size,
                              hipStream_t stream){
  const float* x    = (const float*)d_in[0];
  const float* cond = (const float*)d_in[1];
  const float* mew1 = (const float*)d_in[2];
  const float* meb1 = (const float*)d_in[3];
  const float* mew2 = (const float*)d_in[4];
  const float* meb2 = (const float*)d_in[5];
  const float* qw   = (const float*)d_in[6];
  const float* qb   = (const float*)d_in[7];
  const float* kvw  = (const float*)d_in[8];
  const float* kvb  = (const float*)d_in[9];
  const float* qnw  = (const float*)d_in[10];
  const float* knw  = (const float*)d_in[11];
  const float* ow   = (const float*)d_in[12];
  const float* ob   = (const float*)d_in[13];

  char* ws = (char*)d_ws;
  float*    emb    = (float*)(ws + 0);          // 16x512 f32
  float*    kvpart = (float*)(ws + 32768);      // 16x6144 f32
  float*    kn     = (float*)(ws + 425984);     // 3x1024 f32
  float*    vv     = (float*)(ws + 438272);     // 3x1024 f32
  ushort_t* qwt    = (ushort_t*)(ws + 450560);  // [1024][3072] bf16
  float*    U      = (float*)(ws + 6742016);    // [48][3072] f32
  float*    acoef  = (float*)(ws + 7331840);    // [10560][48] f32
  ushort_t* Qbuf   = (ushort_t*)(ws + 13033472);// [10560][1024] bf16
  float*    h1buf  = (float*)(ws + 34660352);   // 16x512 f32 (old Obuf region)

  // xb (bf16 x) lives in d_out: needed only until the Q-GEMM; k_rank48
  // fully overwrites d_out at the end of every call.
  ushort_t* xb = (ushort_t*)d_out;

  k_pre1<<<8, 256, 0, stream>>>(cond, mew1, meb1, h1buf);
  k_pre2<<<32, 256, 0, stream>>>(h1buf, mew2, meb2, emb);
  k_kv<<<384, 256, 0, stream>>>(emb, kvw, kvpart);
  k_knorm<<<1, 256, 0, stream>>>(kvpart, kvb, knw, kn, vv);
  k_uv<<<288, 512, 0, stream>>>(vv, ow, U);
  k_tconv<<<3072, 256, 0, stream>>>(qw, qwt, 3072, 1024);
  k_xconv<<<2048, 256, 0, stream>>>(x, xb, (TOK * CIMG) / 4);
  gemm8p<0><<<42 * 4, 512, 0, stream>>>(xb, qwt, TOK, CIMG, KHD, qb, nullptr, Qbuf);
  k_attn<<<2640, 256, 0, stream>>>(Qbuf, kn, qnw, acoef);
  k_rank48<<<88 * 12, 256, 0, stream>>>(x, acoef, U, ob, (float*)d_out);
}

// Round 9
// 289.911 us; speedup vs baseline: 1.9123x; 1.2520x over previous
//
#include <hip/hip_runtime.h>

#define TOK  10560
#define CIMG 3072
#define KHD  1024

typedef unsigned short ushort_t;
typedef unsigned int u32;
using bf16x8 = __attribute__((ext_vector_type(8))) __bf16;
using f32x4  = __attribute__((ext_vector_type(4))) float;

#define GLD_LDS16(gp, lp) __builtin_amdgcn_global_load_lds( \
    (const __attribute__((address_space(1))) u32*)(gp), \
    (__attribute__((address_space(3))) u32*)(lp), 16, 0, 0)

static __device__ __forceinline__ unsigned short f2bf(float f){
  union { float f; unsigned u; } x; x.f = f;
  unsigned r = x.u + 0x7fffu + ((x.u >> 16) & 1u);
  return (unsigned short)(r >> 16);
}
static __device__ __forceinline__ float wave_sum(float v){
  #pragma unroll
  for (int off = 32; off > 0; off >>= 1) v += __shfl_xor(v, off, 64);
  return v;
}

// ---------------- conditioning MLP layer 1: h1 = silu(cp@w1+b1) --------------
__global__ __launch_bounds__(256) void k_pre1(const float* __restrict__ cond,
    const float* __restrict__ w1, const float* __restrict__ b1,
    float* __restrict__ h1){
  __shared__ float cs[16][16];
  int t = threadIdx.x;
  if (t < 256) cs[t >> 4][t & 15] = cond[(64 + (t >> 4)) * 16 + (t & 15)];
  __syncthreads();
  #pragma unroll
  for (int i = 0; i < 4; ++i){
    int idx = blockIdx.x * 256 + t + i * 2048;
    int r = idx >> 9, c = idx & 511;
    float s = b1[c];
    #pragma unroll
    for (int j = 0; j < 16; ++j) s += cs[r][j] * w1[j * 512 + c];
    h1[idx] = s / (1.f + __expf(-s));   // silu
  }
}

// ---------------- conditioning MLP layer 2: emb = h1@w2 + b2 -----------------
__global__ __launch_bounds__(256) void k_pre2(const float* __restrict__ h1,
    const float* __restrict__ w2, const float* __restrict__ b2,
    float* __restrict__ emb){
  int idx = blockIdx.x * 256 + threadIdx.x;
  int r = idx >> 9, c = idx & 511;
  const float* hp = h1 + r * 512;
  const float* wp = w2 + c;
  float acc = b2[c];
  #pragma unroll 8
  for (int j = 0; j < 512; ++j) acc += hp[j] * wp[(size_t)j * 512];
  emb[idx] = acc;
}

// ---------------- kv = mf @ kv_w, split-K partials (deterministic) ----------
__global__ __launch_bounds__(256) void k_kv(const float* __restrict__ emb,
                                            const float* __restrict__ kvw,
                                            float* __restrict__ part){
  int bl = blockIdx.x;                 // 3 l * 8 ntile * 16 kchunk = 384
  int l = bl / 128, rem = bl % 128, nt = rem / 16, kc = rem % 16;
  int n = nt * 256 + threadIdx.x;
  const float* e = emb + 2048 * l + kc * 256;   // mf[l][r] = emb[2048l + r]
  const float* w = kvw + (size_t)(kc * 256) * 2048 + n;
  float acc = 0.f;
  for (int r = 0; r < 256; ++r) acc += e[r] * w[(size_t)r * 2048];
  part[kc * 6144 + l * 2048 + n] = acc;
}

// ---------------- reduce partials, bias, k-RMSNorm ---------------------------
__global__ void k_knorm(const float* __restrict__ part, const float* __restrict__ kvb,
                        const float* __restrict__ knw, float* __restrict__ kn,
                        float* __restrict__ vv){
  int wid = threadIdx.x >> 6, lane = threadIdx.x & 63;
  for (int i = 0; i < 12; ++i){
    int g = wid * 12 + i;               // 0..47 = (l,h)
    int l = g >> 4, h = g & 15;
    int ik = l * 2048 + h * 64 + lane;
    float kk = kvb[h * 64 + lane];
    float v  = kvb[1024 + h * 64 + lane];
    for (int p = 0; p < 16; ++p){ kk += part[p * 6144 + ik]; v += part[p * 6144 + ik + 1024]; }
    float ss = wave_sum(kk * kk);
    kn[l * 1024 + h * 64 + lane] = kk * rsqrtf(ss * (1.f/64.f) + 1e-6f) * knw[lane];
    vv[l * 1024 + h * 64 + lane] = v;
  }
}

// ---------------- transpose + f32->bf16 weight convert: dst[C][R] ------------
__global__ __launch_bounds__(256) void k_tconv(const float* __restrict__ src,
                                               ushort_t* __restrict__ dst,
                                               int R, int C){
  __shared__ float tile[32][33];
  int nTr = R >> 5;
  int tr = blockIdx.x % nTr, tc = blockIdx.x / nTr;
  int r0 = tr * 32, c0 = tc * 32, t = threadIdx.x;
  #pragma unroll
  for (int i = 0; i < 4; ++i){
    int idx = t + i * 256; int r = idx >> 5, c = idx & 31;
    tile[r][c] = src[(size_t)(r0 + r) * C + c0 + c];
  }
  __syncthreads();
  #pragma unroll
  for (int i = 0; i < 4; ++i){
    int idx = t + i * 256; int rr = idx >> 5, cc = idx & 31;
    dst[(size_t)(c0 + rr) * R + r0 + cc] = f2bf(tile[cc][rr]);
  }
}

// ---------------- x f32 -> bf16 streaming convert ----------------------------
__global__ __launch_bounds__(256) void k_xconv(const float* __restrict__ x,
                                               ushort_t* __restrict__ xb, int n4){
  for (int i = blockIdx.x * 256 + threadIdx.x; i < n4; i += gridDim.x * 256){
    float4 v = ((const float4*)x)[i];
    ushort4 o;
    o.x = f2bf(v.x); o.y = f2bf(v.y); o.z = f2bf(v.z); o.w = f2bf(v.w);
    ((ushort4*)xb)[i] = o;
  }
}

// ======== 256x256 bf16 MFMA Q-GEMM, 8-phase schedule, FUSED attention ========
// A bf16 [M][K], Bt bf16 [N][K]. Main loop unchanged from round 5 (passing).
// Epilogue: each wave's 128x64 output is exactly one head (64 cols);
// per (m,j) the 4 kg-groups each own one row; 16-lane shfl_xor reduces
// RMSNorm sum-sq and the 3 q.k dots; writes a1,a2 = softmax tail coeffs.
__global__ __launch_bounds__(512, 2) void gemm_fused(
    const ushort_t* __restrict__ A, const ushort_t* __restrict__ Bt,
    int Mdim, int Kdim, int Ndim,
    const float* __restrict__ bias, const float* __restrict__ kn,
    const float* __restrict__ qnw, float* __restrict__ acoef){
  __shared__ __align__(16) unsigned char lds[131072];
  const int tid = threadIdx.x;
  const int lane = tid & 63, wid = tid >> 6;
  const int wm = wid >> 2, wn = wid & 3;     // 2 x 4 waves -> per-wave 128x64
  const int l15 = lane & 15, kg = lane >> 4;
  const int ntiles = Ndim >> 8;

  int bid = blockIdx.x;
  const int cpx = gridDim.x >> 3;
  bid = (bid & 7) * cpx + (bid >> 3);
  const int mt = bid / ntiles, nt = bid % ntiles;
  const int mbase = mt << 8, nbase = nt << 8;

  const int sr  = tid >> 1;                       // 0..255
  const int skh = (tid & 1) ^ ((sr >> 2) & 1);    // inverse swizzle on source
  int arow = mbase + sr; if (arow >= Mdim) arow = Mdim - 1;
  const ushort_t* gA = A  + (size_t)arow * Kdim + skh * 8;
  const ushort_t* gB = Bt + (size_t)(nbase + sr) * Kdim + skh * 8;
  const int wofs = wid * 1024;

  auto stage = [&](int t, int c, int b){
    const int gk = t * 64 + c * 16;
    unsigned char* dst = lds + b * 65536 + c * 8192 + wofs;
    GLD_LDS16(gA + gk, dst);
    GLD_LDS16(gB + gk, dst + 32768);
  };

  const int arl = wm * 128 + l15;
  const int brl = wn * 64 + l15;
  const int kh  = ((kg & 1) ^ ((l15 >> 2) & 1)) * 16;
  const unsigned aBase = (unsigned)((kg >> 1) * 8192 + arl * 32 + kh);
  const unsigned bBase = (unsigned)(32768 + (kg >> 1) * 8192 + brl * 32 + kh);

  f32x4 acc[8][4];
  #pragma unroll
  for (int m = 0; m < 8; ++m)
    #pragma unroll
    for (int n = 0; n < 4; ++n) acc[m][n] = {0.f, 0.f, 0.f, 0.f};

  bf16x8 afr[4], bfr[4];

#define PH_READ_B(base, KSL) { _Pragma("unroll") \
    for (int n = 0; n < 4; ++n) \
      bfr[n] = *(const bf16x8*)((base) + bBase + (KSL)*16384 + n*512); }
#define PH_READ_A(base, KSL, M0) { _Pragma("unroll") \
    for (int m = 0; m < 4; ++m) \
      afr[m] = *(const bf16x8*)((base) + aBase + (KSL)*16384 + ((M0)+m)*512); }
#define PH_MFMA(R0) { __builtin_amdgcn_s_setprio(1); _Pragma("unroll") \
    for (int m = 0; m < 4; ++m){ _Pragma("unroll") \
      for (int n = 0; n < 4; ++n) \
        acc[(R0)+m][n] = __builtin_amdgcn_mfma_f32_16x16x32_bf16(afr[m], bfr[n], acc[(R0)+m][n], 0, 0, 0); } \
    __builtin_amdgcn_s_setprio(0); }

  const int T = Kdim >> 6;

  stage(0, 0, 0); stage(0, 1, 0); stage(0, 2, 0); stage(0, 3, 0);
  asm volatile("s_waitcnt vmcnt(4)" ::: "memory");
  __builtin_amdgcn_s_barrier();

  for (int t = 0; t < T - 1; ++t){
    const int b = t & 1;
    const unsigned char* base = lds + b * 65536;
    PH_READ_B(base, 0); PH_READ_A(base, 0, 0);
    stage(t + 1, 0, b ^ 1);
    __builtin_amdgcn_s_barrier();
    PH_MFMA(0);
    __builtin_amdgcn_s_barrier();
    PH_READ_A(base, 0, 4);
    stage(t + 1, 1, b ^ 1);
    asm volatile("s_waitcnt vmcnt(4)" ::: "memory");
    __builtin_amdgcn_s_barrier();
    PH_MFMA(4);
    __builtin_amdgcn_s_barrier();
    PH_READ_B(base, 1); PH_READ_A(base, 1, 0);
    stage(t + 1, 2, b ^ 1);
    __builtin_amdgcn_s_barrier();
    PH_MFMA(0);
    __builtin_amdgcn_s_barrier();
    PH_READ_A(base, 1, 4);
    stage(t + 1, 3, b ^ 1);
    asm volatile("s_waitcnt vmcnt(4)" ::: "memory");
    __builtin_amdgcn_s_barrier();
    PH_MFMA(4);
    __builtin_amdgcn_s_barrier();
  }
  {
    const unsigned char* base = lds + ((T - 1) & 1) * 65536;
    PH_READ_B(base, 0); PH_READ_A(base, 0, 0);
    __builtin_amdgcn_s_barrier();
    PH_MFMA(0);
    __builtin_amdgcn_s_barrier();
    PH_READ_A(base, 0, 4);
    asm volatile("s_waitcnt vmcnt(0)" ::: "memory");
    __builtin_amdgcn_s_barrier();
    PH_MFMA(4);
    __builtin_amdgcn_s_barrier();
    PH_READ_B(base, 1); PH_READ_A(base, 1, 0);
    PH_MFMA(0);
    PH_READ_A(base, 1, 4);
    PH_MFMA(4);
  }
#undef PH_READ_B
#undef PH_READ_A
#undef PH_MFMA

  // -------- fused attention epilogue (no LDS, no Qbuf) --------
  const int hglob = nt * 4 + wn;            // global head, 0..15
  float qnwv[4], qbv[4], knv0[4], knv1[4], knv2[4];
  #pragma unroll
  for (int n = 0; n < 4; ++n){
    int d = n * 16 + l15;
    qnwv[n] = qnw[d];
    qbv[n]  = bias[nbase + wn * 64 + d];
    knv0[n] = kn[hglob * 64 + d];
    knv1[n] = kn[1024 + hglob * 64 + d];
    knv2[n] = kn[2048 + hglob * 64 + d];
  }
  #pragma unroll
  for (int m = 0; m < 8; ++m){
    #pragma unroll
    for (int j = 0; j < 4; ++j){
      // kg-group 'kg' owns row r = m*16 + kg*4 + j
      float q[4], ssq = 0.f;
      #pragma unroll
      for (int n = 0; n < 4; ++n){ q[n] = acc[m][n][j] + qbv[n]; ssq += q[n] * q[n]; }
      #pragma unroll
      for (int off = 1; off < 16; off <<= 1) ssq += __shfl_xor(ssq, off, 64);
      float rs = rsqrtf(ssq * (1.f/64.f) + 1e-6f);
      float s0 = 0.f, s1 = 0.f, s2 = 0.f;
      #pragma unroll
      for (int n = 0; n < 4; ++n){
        float qn = q[n] * rs * qnwv[n];
        s0 += qn * knv0[n]; s1 += qn * knv1[n]; s2 += qn * knv2[n];
      }
      #pragma unroll
      for (int off = 1; off < 16; off <<= 1){
        s0 += __shfl_xor(s0, off, 64);
        s1 += __shfl_xor(s1, off, 64);
        s2 += __shfl_xor(s2, off, 64);
      }
      s0 *= 0.125f; s1 *= 0.125f; s2 *= 0.125f;
      float mx = fmaxf(s0, fmaxf(s1, s2));
      float e0 = __expf(s0 - mx), e1 = __expf(s1 - mx), e2 = __expf(s2 - mx);
      float inv = 1.f / (e0 + e1 + e2);
      int grow = mbase + wm * 128 + m * 16 + kg * 4 + j;
      if (l15 == 0 && grow < Mdim){
        float2 a12 = {e1 * inv, e2 * inv};
        *(float2*)(acoef + (size_t)grow * 32 + hglob * 2) = a12;
      }
    }
  }
}

// ------- U[h*3+l][c] = sum_d v[l,h,d] * out_w[h*64+d][c]  (48 x 3072, f32) ---
__global__ __launch_bounds__(512) void k_uv(const float* __restrict__ vv,
    const float* __restrict__ ow, float* __restrict__ U){
  int b = blockIdx.x;             // 48 i * 6 cchunk = 288
  int i = b / 6, cc = b % 6;
  int h = i / 3, l = i % 3;
  int c = cc * 512 + threadIdx.x;
  const float* vp = vv + l * 1024 + h * 64;
  const float* wp = ow + (size_t)(h * 64) * 3072 + c;
  float acc = 0.f;
  #pragma unroll
  for (int d = 0; d < 64; ++d) acc += vp[d] * wp[(size_t)d * 3072];
  U[(size_t)i * 3072 + c] = acc;
}

// ------- base[c] = ob[c] + sum_h U[h*3][c];  D[h*2+l'][c] = U[h*3+1+l']-U[h*3]
__global__ __launch_bounds__(256) void k_ubase(const float* __restrict__ U,
    const float* __restrict__ ob, float* __restrict__ base, float* __restrict__ D){
  int c = blockIdx.x * 256 + threadIdx.x;   // 12 blocks
  float b = ob[c];
  #pragma unroll
  for (int h = 0; h < 16; ++h){
    float u0 = U[(size_t)(h * 3 + 0) * 3072 + c];
    float u1 = U[(size_t)(h * 3 + 1) * 3072 + c];
    float u2 = U[(size_t)(h * 3 + 2) * 3072 + c];
    b += u0;
    D[(size_t)(h * 2 + 0) * 3072 + c] = u1 - u0;
    D[(size_t)(h * 2 + 1) * 3072 + c] = u2 - u0;
  }
  base[c] = b;
}

// ------- out = x + base + acoef32 @ D   (rank-32 f32 update, 2 cols/thread) --
// grid: 88 mslices * 6 cchunks; block 256 threads, 2 adjacent cols per thread.
__global__ __launch_bounds__(256) void k_rank32(const float* __restrict__ x,
    const float* __restrict__ acoef, const float* __restrict__ D,
    const float* __restrict__ base, float* __restrict__ out){
  __shared__ __align__(16) float as[120][32];
  const int tid = threadIdx.x;
  const int cc = blockIdx.x % 6, ms = blockIdx.x / 6;
  const int c = cc * 512 + tid * 2;
  const int t0 = ms * 120;

  for (int idx = tid; idx < 1920; idx += 256)
    ((float2*)as)[idx] = ((const float2*)(acoef + (size_t)t0 * 32))[idx];

  float ur0[32], ur1[32];
  #pragma unroll
  for (int i = 0; i < 32; ++i){
    float2 d2 = *(const float2*)(D + (size_t)i * 3072 + c);
    ur0[i] = d2.x; ur1[i] = d2.y;
  }
  float2 b2 = *(const float2*)(base + c);
  __syncthreads();

  #pragma unroll 2
  for (int r = 0; r < 120; ++r){
    const size_t o = (size_t)(t0 + r) * 3072 + c;
    float2 xv = *(const float2*)(x + o);
    float a0 = 0.f, a1 = 0.f;
    const f32x4* ap = (const f32x4*)as[r];
    #pragma unroll
    for (int k = 0; k < 8; ++k){
      f32x4 a4 = ap[k];              // LDS broadcast (same addr all lanes)
      a0 += a4[0]*ur0[4*k] + a4[1]*ur0[4*k+1] + a4[2]*ur0[4*k+2] + a4[3]*ur0[4*k+3];
      a1 += a4[0]*ur1[4*k] + a4[1]*ur1[4*k+1] + a4[2]*ur1[4*k+2] + a4[3]*ur1[4*k+3];
    }
    float2 ov = {xv.x + b2.x + a0, xv.y + b2.y + a1};
    *(float2*)(out + o) = ov;
  }
}

extern "C" void kernel_launch(void* const* d_in, const int* in_sizes, int n_in,
                              void* d_out, int out_size, void* d_ws, size_t ws_size,
                              hipStream_t stream){
  const float* x    = (const float*)d_in[0];
  const float* cond = (const float*)d_in[1];
  const float* mew1 = (const float*)d_in[2];
  const float* meb1 = (const float*)d_in[3];
  const float* mew2 = (const float*)d_in[4];
  const float* meb2 = (const float*)d_in[5];
  const float* qw   = (const float*)d_in[6];
  const float* qb   = (const float*)d_in[7];
  const float* kvw  = (const float*)d_in[8];
  const float* kvb  = (const float*)d_in[9];
  const float* qnw  = (const float*)d_in[10];
  const float* knw  = (const float*)d_in[11];
  const float* ow   = (const float*)d_in[12];
  const float* ob   = (const float*)d_in[13];

  char* ws = (char*)d_ws;
  float*    emb    = (float*)(ws + 0);          // 16x512 f32
  float*    kvpart = (float*)(ws + 32768);      // 16x6144 f32
  float*    kn     = (float*)(ws + 425984);     // 3x1024 f32
  float*    vv     = (float*)(ws + 438272);     // 3x1024 f32
  ushort_t* qwt    = (ushort_t*)(ws + 450560);  // [1024][3072] bf16
  float*    U      = (float*)(ws + 6742016);    // [48][3072] f32
  float*    base   = (float*)(ws + 7331840);    // [3072] f32
  float*    Dbuf   = (float*)(ws + 7344128);    // [32][3072] f32
  float*    acoef  = (float*)(ws + 7737344);    // [10560][32] f32
  float*    h1buf  = (float*)(ws + 9089024);    // 16x512 f32

  // xb (bf16 x) lives in d_out: needed only until the Q-GEMM; k_rank32
  // fully overwrites d_out at the end of every call.
  ushort_t* xb = (ushort_t*)d_out;

  k_pre1<<<8, 256, 0, stream>>>(cond, mew1, meb1, h1buf);
  k_pre2<<<32, 256, 0, stream>>>(h1buf, mew2, meb2, emb);
  k_kv<<<384, 256, 0, stream>>>(emb, kvw, kvpart);
  k_knorm<<<1, 256, 0, stream>>>(kvpart, kvb, knw, kn, vv);
  k_uv<<<288, 512, 0, stream>>>(vv, ow, U);
  k_ubase<<<12, 256, 0, stream>>>(U, ob, base, Dbuf);
  k_tconv<<<3072, 256, 0, stream>>>(qw, qwt, 3072, 1024);
  k_xconv<<<2048, 256, 0, stream>>>(x, xb, (TOK * CIMG) / 4);
  gemm_fused<<<42 * 4, 512, 0, stream>>>(xb, qwt, TOK, CIMG, KHD, qb, kn, qnw, acoef);
  k_rank32<<<88 * 6, 256, 0, stream>>>(x, acoef, Dbuf, base, (float*)d_out);
}